// Round 6
// baseline (97.135 us; speedup 1.0000x reference)
//
#include <hip/hip_runtime.h>
#include <math.h>

#define NUM_RBF 64
#define N_GRAPHS 64
#define QCAP     1032     /* 1024 max survivors/round + tail slack */

typedef int   int4v   __attribute__((ext_vector_type(4)));
typedef float float4v __attribute__((ext_vector_type(4)));

// Stage 0 : fused table C = rbf_params * radial_filters  AND packed node
//           records {x,y,z, type|batch<<8} in one launch.
// Stage 1 : edge energy with IN-BLOCK SURVIVOR COMPACTION:
//           push phase  — 4 edges/thread, d^2-only cutoff test, survivor
//                         records (d2, pair|bin<<10) appended to an LDS
//                         queue (ballot + mbcnt prefix + 1 LDS atomic/wave);
//           drain phase — queue processed at ~full lane density: sqrt, 12-tap
//                         Gaussian window via multiplicative recurrence
//                         (3 exps + 1 cos), dense table gathers, LDS bins.
// Stage 2 : reduce partials -> d_out (writes all 64 outputs; poison-safe).

__global__ __launch_bounds__(256) void prologue_kernel(
    const float4v* __restrict__ p, const float4v* __restrict__ f,
    float4v* __restrict__ C, int n4,
    const float* __restrict__ pos, const int* __restrict__ types,
    const int* __restrict__ batch, float4v* __restrict__ rec, int N)
{
    int i = blockIdx.x * blockDim.x + threadIdx.x;
    if (i < n4) C[i] = p[i] * f[i];
    if (i < N) {
        int bits = (types[i] & 0xFF) | ((batch[i] & 0xFF) << 8);
        float4v r = { pos[3 * i], pos[3 * i + 1], pos[3 * i + 2],
                      __int_as_float(bits) };
        rec[i] = r;
    }
}

#define CUTOFF2_F     25.0f
#define GAMMA_F       163.84f                    /* (64/5)^2                  */
#define SPACING_F     (float)(5.0 / 63.0)
#define INV_SPACING_F (float)(63.0 / 5.0)
#define PI_OVER_C_F   (float)(3.14159265358979323846 / 5.0)
#define TWO_GAMMA_S_F (float)(2.0 * 163.84 * 5.0 / 63.0)   /* 26.00635 */
#define LN_V          (-(64.0 / 63.0) * (64.0 / 63.0))
#define V_1           (float)exp(LN_V)           /* v                         */
#define V_2           (float)exp(2.0 * LN_V)     /* v^2 per-step multiplier   */

// Dense window evaluation for one survivor record.
__device__ __forceinline__ void window_body(
    float d2, int meta, const float4v* __restrict__ C4,
    float* __restrict__ bins)
{
    const float d    = sqrtf(d2);
    const int   base = (meta & 1023) << 6;       // pair * NUM_RBF
    const int   bin  = meta >> 10;

    const float c = d * INV_SPACING_F;
    int a0 = ((int)floorf(c - 3.5f)) & ~3;
    a0 = max(0, min(NUM_RBF - 12, a0));

    const float4v* w = C4 + ((base + a0) >> 2);
    const float4v w0 = w[0], w1 = w[1], w2 = w[2];

    // taps t_k = exp(-gamma*(delta-k*s)^2), anchored at k=5 (verified R5):
    const float delta = d - (float)a0 * SPACING_F;
    const float d5 = delta - 5.0f * SPACING_F;
    const float t5 = __expf(-GAMMA_F * d5 * d5);
    const float x  = TWO_GAMMA_S_F * d5;
    const float u  = __expf(x);
    const float ui = __expf(-x);

    float acc = w1.y * t5;                 // k=5
    float t = t5, m = u * V_1;             // upward k=6..11
    t *= m;  acc += w1.z * t;  m *= V_2;
    t *= m;  acc += w1.w * t;  m *= V_2;
    t *= m;  acc += w2.x * t;  m *= V_2;
    t *= m;  acc += w2.y * t;  m *= V_2;
    t *= m;  acc += w2.z * t;  m *= V_2;
    t *= m;  acc += w2.w * t;
    t = t5;  m = ui * V_1;                 // downward k=4..0
    t *= m;  acc += w1.x * t;  m *= V_2;
    t *= m;  acc += w0.w * t;  m *= V_2;
    t *= m;  acc += w0.z * t;  m *= V_2;
    t *= m;  acc += w0.y * t;  m *= V_2;
    t *= m;  acc += w0.x * t;

    const float fc = 0.5f * (__cosf(PI_OVER_C_F * d) + 1.0f);
    atomicAdd(&bins[bin], acc * fc);
}

// Push phase: cutoff test + survivor append (all 64 lanes reach the ballot).
__device__ __forceinline__ void push_body(
    float4v rs, float4v rd, int T,
    float* __restrict__ qd, int* __restrict__ qm, int* __restrict__ qcnt)
{
    const float dx = rd.x - rs.x;
    const float dy = rd.y - rs.y;
    const float dz = rd.z - rs.z;
    const float d2 = dx * dx + dy * dy + dz * dz + 1e-12f;
    const bool alive = d2 < CUTOFF2_F;

    const unsigned long long mask = __ballot(alive);
    if (alive) {
        const int sb = __float_as_int(rs.w);
        const int ts = sb & 0xFF;
        const int td = __float_as_int(rd.w) & 0xFF;
        const int lo = min(ts, td);
        const int hi = max(ts, td);
        const int meta = (lo * T + hi) | (((sb >> 8) & 0x3F) << 10);

        const int prefix = __builtin_amdgcn_mbcnt_hi(
            (unsigned)(mask >> 32),
            __builtin_amdgcn_mbcnt_lo((unsigned)mask, 0));
        const int first = __ffsll((unsigned long long)mask) - 1;
        int off = 0;
        if (((int)(threadIdx.x & 63)) == first)
            off = atomicAdd(qcnt, (int)__popcll(mask));
        off = __shfl(off, first, 64);
        qd[off + prefix] = d2;
        qm[off + prefix] = meta;
    }
}

__global__ __launch_bounds__(256) void edge_energy_kernel(
    const int*     __restrict__ edge_index,
    const float4v* __restrict__ rec,
    const float4v* __restrict__ C4,
    float*         __restrict__ partial,
    int E, int T)
{
    __shared__ float bins[N_GRAPHS];
    __shared__ float qd[QCAP];
    __shared__ int   qm[QCAP];
    __shared__ int   qcnt;

    const int tid = threadIdx.x;
    for (int i = tid; i < N_GRAPHS; i += blockDim.x) bins[i] = 0.0f;
    if (tid == 0) qcnt = 0;
    __syncthreads();

    const int nfull = E >> 2;

    // tail edges (E % 4): fully processed by one thread, no queue
    if (blockIdx.x == 0 && tid == 0) {
        for (int e = nfull << 2; e < E; ++e) {
            const float4v rs = rec[edge_index[e]];
            const float4v rd = rec[edge_index[E + e]];
            const float dx = rd.x - rs.x, dy = rd.y - rs.y, dz = rd.z - rs.z;
            const float d2 = dx * dx + dy * dy + dz * dz + 1e-12f;
            if (d2 < CUTOFF2_F) {
                const int sb = __float_as_int(rs.w);
                const int ts = sb & 0xFF;
                const int td = __float_as_int(rd.w) & 0xFF;
                const int meta = (min(ts, td) * T + max(ts, td))
                               | (((sb >> 8) & 0x3F) << 10);
                window_body(d2, meta, C4, bins);
            }
        }
    }

    const int bstride = gridDim.x * blockDim.x;
    for (int q0 = blockIdx.x * blockDim.x; q0 < nfull; q0 += bstride) {
        const int q = q0 + tid;
        if (q < nfull) {
            const int e0 = q << 2;
            // nontemporal: 12.8 MB once-streamed index data must not evict
            // the hot node-record / table working set from L2
            const int4v sv = __builtin_nontemporal_load(
                (const int4v*)(edge_index + e0));
            const int4v tv = __builtin_nontemporal_load(
                (const int4v*)(edge_index + E + e0));

            const float4v rs0 = rec[sv.x], rd0 = rec[tv.x];
            const float4v rs1 = rec[sv.y], rd1 = rec[tv.y];
            const float4v rs2 = rec[sv.z], rd2 = rec[tv.z];
            const float4v rs3 = rec[sv.w], rd3 = rec[tv.w];

            push_body(rs0, rd0, T, qd, qm, &qcnt);
            push_body(rs1, rd1, T, qd, qm, &qcnt);
            push_body(rs2, rd2, T, qd, qm, &qcnt);
            push_body(rs3, rd3, T, qd, qm, &qcnt);
        }

        __syncthreads();                 // pushes visible
        const int n = qcnt;
        __syncthreads();                 // everyone captured n
        if (tid == 0) qcnt = 0;
        for (int i = tid; i < n; i += 256)
            window_body(qd[i], qm[i], C4, bins);
        __syncthreads();                 // drain done; qcnt reset visible
    }

    for (int i = tid; i < N_GRAPHS; i += blockDim.x)
        partial[blockIdx.x * N_GRAPHS + i] = bins[i];
}

__global__ __launch_bounds__(256) void reduce_kernel(
    const float* __restrict__ partial, float* __restrict__ out, int nblocks)
{
    const int g = blockIdx.x;
    float s = 0.0f;
    for (int i = threadIdx.x; i < nblocks; i += blockDim.x)
        s += partial[i * N_GRAPHS + g];

    for (int off = 32; off > 0; off >>= 1)
        s += __shfl_down(s, off, 64);

    __shared__ float red[4];
    const int wave = threadIdx.x >> 6;
    const int lane = threadIdx.x & 63;
    if (lane == 0) red[wave] = s;
    __syncthreads();
    if (threadIdx.x == 0)
        out[g] = red[0] + red[1] + red[2] + red[3];
}

extern "C" void kernel_launch(void* const* d_in, const int* in_sizes, int n_in,
                              void* d_out, int out_size, void* d_ws, size_t ws_size,
                              hipStream_t stream) {
    const float* pos            = (const float*)d_in[0];
    const float* rbf_params     = (const float*)d_in[1];
    const float* radial_filters = (const float*)d_in[2];
    const int*   edge_index     = (const int*)d_in[3];
    const int*   atom_types     = (const int*)d_in[4];
    const int*   batch          = (const int*)d_in[5];
    float*       out            = (float*)d_out;

    const int E = in_sizes[3] / 2;
    const int N = in_sizes[4];
    int T = 1;
    while ((T + 1) * (T + 1) * NUM_RBF <= in_sizes[1]) ++T;
    const int tbl_elems = T * T * NUM_RBF;          // multiple of 4

    // workspace layout (256B aligned): [table | node recs | partials]
    float*   Ctab    = (float*)d_ws;
    float4v* recs    = (float4v*)((char*)d_ws + ((size_t)tbl_elems * 4 + 255) / 256 * 256);
    float*   partial = (float*)((char*)recs + (size_t)N * 16);

    const int nq = E >> 2;
    int nblocks = (nq + 255) / 256;                 // one quad per thread
    const size_t part_off = (size_t)((char*)partial - (char*)d_ws);
    const size_t avail = (ws_size > part_off) ? (ws_size - part_off) : 0;
    const int maxb = (int)(avail / (N_GRAPHS * sizeof(float)));
    if (nblocks > maxb) nblocks = maxb > 0 ? maxb : 1;
    if (nblocks < 1) nblocks = 1;

    const int pro_n = max(tbl_elems / 4, N);
    prologue_kernel<<<(pro_n + 255) / 256, 256, 0, stream>>>(
        (const float4v*)rbf_params, (const float4v*)radial_filters,
        (float4v*)Ctab, tbl_elems / 4, pos, atom_types, batch, recs, N);
    edge_energy_kernel<<<nblocks, 256, 0, stream>>>(
        edge_index, recs, (const float4v*)Ctab, partial, E, T);
    reduce_kernel<<<N_GRAPHS, 256, 0, stream>>>(partial, out, nblocks);
}